// Round 1
// baseline (2452.328 us; speedup 1.0000x reference)
//
#include <hip/hip_runtime.h>
#include <cstdint>
#include <cstddef>

// ---------------------------------------------------------------------------
// TinyViT block (window attention + dwconv/BN + MLP) for MI355X / gfx950.
// Layout plan:
//   tokens are window-ordered: token = win*49 + n, win = ((b*8+wh)*8+ww),
//   n = r*7+c, spatial (h,w) = (wh*7+r, ww*7+c). 56 = 8*7 exactly (no pad).
// All GEMMs are A[M,K] x Bt[N,K]^T with bf16 inputs / fp32 accum (MFMA
// 16x16x32), M multiples of 128, N in {384,1152,1536}, K in {384,1536}.
// ---------------------------------------------------------------------------

typedef __bf16 bf16x8 __attribute__((ext_vector_type(8)));
typedef float  f32x4  __attribute__((ext_vector_type(4)));

#define DEVI __device__ __forceinline__

static constexpr int   C_    = 384;
static constexpr int   HW_   = 3136;      // 56*56
static constexpr int   NB_   = 32;        // batch
static constexpr int   NTOK  = 100352;    // 32*3136
static constexpr float EPS_  = 1e-5f;
static constexpr float ASCAL = 0.17677669529663689f;  // 32^-0.5

DEVI void gld16(const void* g, void* l) {
  __builtin_amdgcn_global_load_lds((__attribute__((address_space(1))) void*)(g),
                                   (__attribute__((address_space(3))) void*)(l),
                                   16, 0, 0);
}

// ---------------------------------------------------------------------------
// GEMM: C[m,n] = epi( sum_k A[m,k]*Bt[n,k] + bias[n] )
// EPI: 0 = bf16 out, 1 = bf16 out with exact gelu, 2 = f32 out
// ---------------------------------------------------------------------------
template <int EPI>
__global__ __launch_bounds__(256)
void gemm_bt(const __bf16* __restrict__ A, const __bf16* __restrict__ Bt,
             const float* __restrict__ bias, void* __restrict__ outp,
             int M, int N, int K)
{
  __shared__ __align__(16) __bf16 As[128 * 32];
  __shared__ __align__(16) __bf16 Bs[128 * 32];

  const int tid  = threadIdx.x;
  const int lane = tid & 63;
  const int wave = tid >> 6;
  const int quad = lane >> 4;
  const int l16  = lane & 15;
  const int wr   = (wave >> 1) * 64;
  const int wc   = (wave & 1) * 64;
  const size_t m0 = (size_t)blockIdx.y * 128;
  const size_t n0 = (size_t)blockIdx.x * 128;

  // staging: thread t covers 16B chunks t and t+256 of each 8KB tile.
  // chunk c -> row c>>2, k-offset (c&3)*8 elems; LDS is row-major [128][32].
  const int srow = tid >> 2;
  const int skc  = (tid & 3) * 8;
  const __bf16* ga0 = A  + (m0 + srow) * (size_t)K + skc;
  const __bf16* ga1 = ga0 + (size_t)64 * K;
  const __bf16* gb0 = Bt + (n0 + srow) * (size_t)K + skc;
  const __bf16* gb1 = gb0 + (size_t)64 * K;
  __bf16* la0 = As + tid * 8;
  __bf16* la1 = As + 2048 + tid * 8;
  __bf16* lb0 = Bs + tid * 8;
  __bf16* lb1 = Bs + 2048 + tid * 8;

  f32x4 acc[4][4] = {};

  const int kiters = K >> 5;
  for (int kb = 0; kb < kiters; ++kb) {
    gld16(ga0, la0); gld16(ga1, la1);
    gld16(gb0, lb0); gld16(gb1, lb1);
    ga0 += 32; ga1 += 32; gb0 += 32; gb1 += 32;
    __syncthreads();   // drains vmcnt (global_load_lds) for all waves
    bf16x8 af[4], bfr[4];
#pragma unroll
    for (int i = 0; i < 4; ++i)
      af[i] = *(const bf16x8*)(As + (wr + i * 16 + l16) * 32 + quad * 8);
#pragma unroll
    for (int j = 0; j < 4; ++j)
      bfr[j] = *(const bf16x8*)(Bs + (wc + j * 16 + l16) * 32 + quad * 8);
#pragma unroll
    for (int i = 0; i < 4; ++i)
#pragma unroll
      for (int j = 0; j < 4; ++j)
        acc[i][j] = __builtin_amdgcn_mfma_f32_16x16x32_bf16(af[i], bfr[j], acc[i][j], 0, 0, 0);
    __syncthreads();   // protect LDS from next iteration's staging
  }

  // C/D layout: col = lane&15, row = (lane>>4)*4 + reg   [measured m89/m91]
#pragma unroll
  for (int j = 0; j < 4; ++j) {
    const size_t ng = n0 + wc + j * 16 + l16;
    const float bv = bias[ng];
#pragma unroll
    for (int i = 0; i < 4; ++i) {
      const size_t mg = m0 + wr + i * 16 + quad * 4;
#pragma unroll
      for (int r = 0; r < 4; ++r) {
        float v = acc[i][j][r] + bv;
        if (EPI == 1) v = 0.5f * v * (1.0f + erff(v * 0.70710678118654752f));
        if (EPI == 2) ((float*)outp)[(mg + r) * N + ng] = v;
        else          ((__bf16*)outp)[(mg + r) * N + ng] = (__bf16)v;
      }
    }
  }
}

// ---------------------------------------------------------------------------
// Per-token LayerNorm statistics (x in NCHW, coalesced over hw).
// ---------------------------------------------------------------------------
__global__ __launch_bounds__(256)
void ln_stats(const float* __restrict__ x, float* __restrict__ mean,
              float* __restrict__ rstd)
{
  const int b  = blockIdx.y;
  const int hw = blockIdx.x * 256 + threadIdx.x;
  if (hw >= HW_) return;
  const float* p = x + (size_t)b * (C_ * HW_) + hw;
  float s = 0.f, ss = 0.f;
  for (int c = 0; c < C_; ++c) {
    float v = p[(size_t)c * HW_];
    s += v; ss = fmaf(v, v, ss);
  }
  float mu  = s * (1.0f / C_);
  float var = ss * (1.0f / C_) - mu * mu;
  mean[b * HW_ + hw] = mu;
  rstd[b * HW_ + hw] = rsqrtf(var + EPS_);
}

// ---------------------------------------------------------------------------
// fp32 weight -> bf16 copies (qkv_w, proj_w, w1, w2), one launch.
// ---------------------------------------------------------------------------
__global__ __launch_bounds__(256)
void convert_weights(const float* __restrict__ a, const float* __restrict__ b,
                     const float* __restrict__ c, const float* __restrict__ d,
                     __bf16* __restrict__ oa, __bf16* __restrict__ ob,
                     __bf16* __restrict__ oc, __bf16* __restrict__ od)
{
  int i = blockIdx.x * 256 + threadIdx.x;
  if      (i < 442368)  oa[i] = (__bf16)a[i];
  else if (i < 589824)  ob[i - 442368]  = (__bf16)b[i - 442368];
  else if (i < 1179648) oc[i - 589824]  = (__bf16)c[i - 589824];
  else if (i < 1769472) od[i - 1179648] = (__bf16)d[i - 1179648];
}

// ---------------------------------------------------------------------------
// NCHW -> window-token-major bf16 (optionally with LayerNorm). One window
// per block; LDS 64ch x 49tok tile transpose (stride 49 -> conflict-free).
// ---------------------------------------------------------------------------
template <bool LN>
__global__ __launch_bounds__(256)
void win_gather(const float* __restrict__ src, const float* __restrict__ mean,
                const float* __restrict__ rstd, const float* __restrict__ gamma,
                const float* __restrict__ beta, __bf16* __restrict__ dst, int w0)
{
  const int win = w0 + blockIdx.x;
  const int b = win >> 6, wi = win & 63;
  const int hw0 = ((wi >> 3) * 56 + (wi & 7)) * 7;
  const float* xb = src + (size_t)b * (C_ * HW_) + hw0;
  const int tid = threadIdx.x;

  __shared__ float tile[64 * 49];
  __shared__ float mu_s[49], rs_s[49];
  if (LN && tid < 49) {
    int hw = hw0 + (tid / 7) * 56 + (tid % 7);
    mu_s[tid] = mean[b * HW_ + hw];
    rs_s[tid] = rstd[b * HW_ + hw];
  }
  for (int cb = 0; cb < C_; cb += 64) {
    for (int e = tid; e < 3136; e += 256) {      // e = cc*49 + n
      int cc = e / 49, n = e - cc * 49;
      tile[e] = xb[(size_t)(cb + cc) * HW_ + (n / 7) * 56 + (n % 7)];
    }
    __syncthreads();
    for (int e = tid; e < 3136; e += 256) {      // e = n*64 + cc
      int n = e >> 6, cc = e & 63;
      int ch = cb + cc;
      float v = tile[cc * 49 + n];
      if (LN) v = (v - mu_s[n]) * rs_s[n] * gamma[ch] + beta[ch];
      dst[((size_t)blockIdx.x * 49 + n) * C_ + ch] = (__bf16)v;
    }
    __syncthreads();
  }
}

// ---------------------------------------------------------------------------
// token-major fp32 [MC,384] -> NCHW.  MODE 0: out = xin + src (shortcut add)
//                                     MODE 1: out += src      (MLP residual)
// ---------------------------------------------------------------------------
template <int MODE>
__global__ __launch_bounds__(256)
void win_scatter(const float* __restrict__ src, const float* __restrict__ xin,
                 float* __restrict__ outp, int w0)
{
  const int win = w0 + blockIdx.x;
  const int b = win >> 6, wi = win & 63;
  const int hw0 = ((wi >> 3) * 56 + (wi & 7)) * 7;
  const size_t pbase = (size_t)b * (C_ * HW_) + hw0;
  const int tid = threadIdx.x;
  __shared__ float tile[64 * 49];

  for (int cb = 0; cb < C_; cb += 64) {
    for (int e = tid; e < 3136; e += 256) {      // e = n*64 + cc, coalesced read
      int n = e >> 6, cc = e & 63;
      tile[cc * 49 + n] = src[((size_t)blockIdx.x * 49 + n) * C_ + cb + cc];
    }
    __syncthreads();
    for (int e = tid; e < 3136; e += 256) {      // e = cc*49 + n
      int cc = e / 49, n = e - cc * 49;
      size_t idx = pbase + (size_t)(cb + cc) * HW_ + (n / 7) * 56 + (n % 7);
      float v = tile[e];
      if (MODE == 0) outp[idx] = xin[idx] + v;
      else           outp[idx] += v;
    }
    __syncthreads();
  }
}

// ---------------------------------------------------------------------------
// Window attention, one wave per (window, head). K,V staged fp32 in LDS;
// each of 49 lanes owns one query row fully in registers (q/p/o), so softmax
// is register-only and all LDS reads are same-address broadcasts (free).
// ---------------------------------------------------------------------------
__global__ __launch_bounds__(64)
void attn_win(const __bf16* __restrict__ qkv, const float* __restrict__ btab,
              __bf16* __restrict__ attn_out)
{
  const int head = blockIdx.x;
  const int wl   = blockIdx.y;
  const int lane = threadIdx.x;

  __shared__ __align__(16) float ks[49 * 32];
  __shared__ __align__(16) float vs[49 * 32];
  __shared__ float bs[169];

  const __bf16* base = qkv + (size_t)wl * 49 * 1152 + head * 32;
  for (int e = lane; e < 1568; e += 64) {
    int n = e >> 5, d = e & 31;
    const __bf16* rowp = base + (size_t)n * 1152;
    ks[e] = (float)rowp[384 + d];
    vs[e] = (float)rowp[768 + d];
  }
  for (int e = lane; e < 169; e += 64) bs[e] = btab[e * 12 + head];
  __syncthreads();

  if (lane >= 49) return;
  const int ri = lane / 7, ci = lane % 7;
  float q[32];
  const __bf16* qp = base + (size_t)lane * 1152;
#pragma unroll
  for (int d = 0; d < 32; ++d) q[d] = (float)qp[d] * ASCAL;

  float p[49];
  float mx = -1e30f;
#pragma unroll
  for (int j = 0; j < 49; ++j) {
    float s = bs[(ri - j / 7 + 6) * 13 + (ci - j % 7 + 6)];
    const float* kj = ks + j * 32;
#pragma unroll
    for (int d = 0; d < 32; ++d) s = fmaf(q[d], kj[d], s);
    p[j] = s;
    mx = fmaxf(mx, s);
  }
  float sum = 0.f;
#pragma unroll
  for (int j = 0; j < 49; ++j) { float e = __expf(p[j] - mx); p[j] = e; sum += e; }
  const float inv = 1.0f / sum;

  float o[32];
#pragma unroll
  for (int d = 0; d < 32; ++d) o[d] = 0.f;
#pragma unroll
  for (int j = 0; j < 49; ++j) {
    const float pj = p[j];
    const float* vj = vs + j * 32;
#pragma unroll
    for (int d = 0; d < 32; ++d) o[d] = fmaf(pj, vj[d], o[d]);
  }
  __bf16* op = attn_out + ((size_t)wl * 49 + lane) * 384 + head * 32;
#pragma unroll
  for (int g = 0; g < 4; ++g) {
    bf16x8 t;
#pragma unroll
    for (int u = 0; u < 8; ++u) t[u] = (__bf16)(o[g * 8 + u] * inv);
    *(bf16x8*)(op + g * 8) = t;
  }
}

// ---------------------------------------------------------------------------
// Depthwise 3x3 conv (pad 1) + inference BN; writes seq2 straight into d_out.
// One (b,c) plane per blockIdx.y -> L1-resident 12.5KB plane.
// ---------------------------------------------------------------------------
__global__ __launch_bounds__(256)
void dwconv_bn(const float* __restrict__ xc, const float* __restrict__ cw,
               const float* __restrict__ g, const float* __restrict__ bta,
               const float* __restrict__ mn, const float* __restrict__ vr,
               float* __restrict__ outp)
{
  const int bc = blockIdx.y;
  const int hw = blockIdx.x * 256 + threadIdx.x;
  if (hw >= HW_) return;
  const int c = bc % C_;
  const float* pl = xc + (size_t)bc * HW_;
  const int h = hw / 56, w = hw - h * 56;
  float a = 0.f;
#pragma unroll
  for (int kh = 0; kh < 3; ++kh) {
    int hh = h + kh - 1;
    if (hh < 0 || hh >= 56) continue;
#pragma unroll
    for (int kw = 0; kw < 3; ++kw) {
      int ww = w + kw - 1;
      if (ww < 0 || ww >= 56) continue;
      a = fmaf(cw[c * 9 + kh * 3 + kw], pl[hh * 56 + ww], a);
    }
  }
  float sc = g[c] * rsqrtf(vr[c] + EPS_);
  outp[(size_t)bc * HW_ + hw] = (a - mn[c]) * sc + bta[c];
}

// ---------------------------------------------------------------------------
extern "C" void kernel_launch(void* const* d_in, const int* in_sizes, int n_in,
                              void* d_out, int out_size, void* d_ws, size_t ws_size,
                              hipStream_t stream)
{
  const float* x      = (const float*)d_in[0];
  const float* ln_g   = (const float*)d_in[1];
  const float* ln_b   = (const float*)d_in[2];
  const float* qkv_w  = (const float*)d_in[3];
  const float* qkv_b  = (const float*)d_in[4];
  const float* proj_w = (const float*)d_in[5];
  const float* proj_b = (const float*)d_in[6];
  const float* btab   = (const float*)d_in[7];
  const float* conv_w = (const float*)d_in[8];
  const float* bn_g   = (const float*)d_in[9];
  const float* bn_b   = (const float*)d_in[10];
  const float* bn_m   = (const float*)d_in[11];
  const float* bn_v   = (const float*)d_in[12];
  const float* w1     = (const float*)d_in[13];
  const float* b1     = (const float*)d_in[14];
  const float* w2     = (const float*)d_in[15];
  const float* b2     = (const float*)d_in[16];
  float* out = (float*)d_out;

  size_t off = 0;
  auto alloc = [&](size_t bytes) -> void* {
    void* p = (char*)d_ws + off;
    off += (bytes + 255) & ~(size_t)255;
    return p;
  };
  float*  meanb = (float*)alloc((size_t)NTOK * 4);
  float*  rstdb = (float*)alloc((size_t)NTOK * 4);
  __bf16* wqb   = (__bf16*)alloc((size_t)1152 * 384 * 2);
  __bf16* wpb   = (__bf16*)alloc((size_t)384  * 384 * 2);
  __bf16* w1b   = (__bf16*)alloc((size_t)1536 * 384 * 2);
  __bf16* w2b   = (__bf16*)alloc((size_t)384  * 1536 * 2);
  float*  xconv = (float*)alloc((size_t)NTOK * C_ * 4);

  // Chunk size (tokens) chosen so all chunk buffers fit in ws. 6144 B/token.
  int MC = 6272;
  const int opts[5] = {100352, 50176, 25088, 12544, 6272};
  for (int i = 0; i < 5; ++i)
    if (off + (size_t)opts[i] * 6144 + 8192 <= ws_size) { MC = opts[i]; break; }

  __bf16* xn   = (__bf16*)alloc((size_t)MC * 384 * 2);   // also seq2 tokens
  __bf16* qkvb = (__bf16*)alloc((size_t)MC * 1536 * 2);  // qkv, later MLP h
  __bf16* attb = (__bf16*)alloc((size_t)MC * 384 * 2);
  float*  ptmp = (float*)alloc((size_t)MC * 384 * 4);    // proj out / mlp2 out

  const int nchunks = NTOK / MC;
  const int wpc = MC / 49;   // windows per chunk

  convert_weights<<<6912, 256, 0, stream>>>(qkv_w, proj_w, w1, w2, wqb, wpb, w1b, w2b);
  ln_stats<<<dim3(13, NB_), 256, 0, stream>>>(x, meanb, rstdb);

  for (int ci = 0; ci < nchunks; ++ci) {
    const int w0 = ci * wpc;
    win_gather<true><<<wpc, 256, 0, stream>>>(x, meanb, rstdb, ln_g, ln_b, xn, w0);
    gemm_bt<0><<<dim3(9, MC / 128), 256, 0, stream>>>(xn, wqb, qkv_b, qkvb, MC, 1152, 384);
    attn_win<<<dim3(12, wpc), 64, 0, stream>>>(qkvb, btab, attb);
    gemm_bt<2><<<dim3(3, MC / 128), 256, 0, stream>>>(attb, wpb, proj_b, ptmp, MC, 384, 384);
    win_scatter<0><<<wpc, 256, 0, stream>>>(ptmp, x, xconv, w0);
  }

  dwconv_bn<<<dim3(13, NB_ * C_), 256, 0, stream>>>(xconv, conv_w, bn_g, bn_b, bn_m, bn_v, out);

  for (int ci = 0; ci < nchunks; ++ci) {
    const int w0 = ci * wpc;
    win_gather<false><<<wpc, 256, 0, stream>>>(out, nullptr, nullptr, nullptr, nullptr, xn, w0);
    gemm_bt<1><<<dim3(12, MC / 128), 256, 0, stream>>>(xn, w1b, b1, qkvb, MC, 1536, 384);
    gemm_bt<2><<<dim3(3, MC / 128), 256, 0, stream>>>(qkvb, w2b, b2, ptmp, MC, 384, 1536);
    win_scatter<1><<<wpc, 256, 0, stream>>>(ptmp, nullptr, out, w0);
  }
}

// Round 2
// 2222.102 us; speedup vs baseline: 1.1036x; 1.1036x over previous
//
#include <hip/hip_runtime.h>
#include <cstdint>
#include <cstddef>

// ---------------------------------------------------------------------------
// TinyViT block (window attention + dwconv/BN + MLP) for MI355X / gfx950.
// Layout plan:
//   tokens are window-ordered: token = win*49 + n, win = ((b*8+wh)*8+ww),
//   n = r*7+c, spatial (h,w) = (wh*7+r, ww*7+c). 56 = 8*7 exactly (no pad).
// All GEMMs are A[M,K] x Bt[N,K]^T with bf16 inputs / fp32 accum (MFMA
// 16x16x32), M multiples of 128, N in {384,1152,1536}, K in {384,1536}.
// R2: dwconv_bn LDS-staged (was latency-bound at 1TB/s, 9 scalar loads/px);
//     seq (conv input) stored bf16 -> fixed ws 158->82MB -> MC 12544->25088.
// ---------------------------------------------------------------------------

typedef __bf16 bf16x8 __attribute__((ext_vector_type(8)));
typedef float  f32x4  __attribute__((ext_vector_type(4)));

#define DEVI __device__ __forceinline__

static constexpr int   C_    = 384;
static constexpr int   HW_   = 3136;      // 56*56
static constexpr int   NB_   = 32;        // batch
static constexpr int   NTOK  = 100352;    // 32*3136
static constexpr float EPS_  = 1e-5f;
static constexpr float ASCAL = 0.17677669529663689f;  // 32^-0.5

DEVI void gld16(const void* g, void* l) {
  __builtin_amdgcn_global_load_lds((__attribute__((address_space(1))) void*)(g),
                                   (__attribute__((address_space(3))) void*)(l),
                                   16, 0, 0);
}

// ---------------------------------------------------------------------------
// GEMM: C[m,n] = epi( sum_k A[m,k]*Bt[n,k] + bias[n] )
// EPI: 0 = bf16 out, 1 = bf16 out with exact gelu, 2 = f32 out
// ---------------------------------------------------------------------------
template <int EPI>
__global__ __launch_bounds__(256)
void gemm_bt(const __bf16* __restrict__ A, const __bf16* __restrict__ Bt,
             const float* __restrict__ bias, void* __restrict__ outp,
             int M, int N, int K)
{
  __shared__ __align__(16) __bf16 As[128 * 32];
  __shared__ __align__(16) __bf16 Bs[128 * 32];

  const int tid  = threadIdx.x;
  const int lane = tid & 63;
  const int wave = tid >> 6;
  const int quad = lane >> 4;
  const int l16  = lane & 15;
  const int wr   = (wave >> 1) * 64;
  const int wc   = (wave & 1) * 64;
  const size_t m0 = (size_t)blockIdx.y * 128;
  const size_t n0 = (size_t)blockIdx.x * 128;

  const int srow = tid >> 2;
  const int skc  = (tid & 3) * 8;
  const __bf16* ga0 = A  + (m0 + srow) * (size_t)K + skc;
  const __bf16* ga1 = ga0 + (size_t)64 * K;
  const __bf16* gb0 = Bt + (n0 + srow) * (size_t)K + skc;
  const __bf16* gb1 = gb0 + (size_t)64 * K;
  __bf16* la0 = As + tid * 8;
  __bf16* la1 = As + 2048 + tid * 8;
  __bf16* lb0 = Bs + tid * 8;
  __bf16* lb1 = Bs + 2048 + tid * 8;

  f32x4 acc[4][4] = {};

  const int kiters = K >> 5;
  for (int kb = 0; kb < kiters; ++kb) {
    gld16(ga0, la0); gld16(ga1, la1);
    gld16(gb0, lb0); gld16(gb1, lb1);
    ga0 += 32; ga1 += 32; gb0 += 32; gb1 += 32;
    __syncthreads();
    bf16x8 af[4], bfr[4];
#pragma unroll
    for (int i = 0; i < 4; ++i)
      af[i] = *(const bf16x8*)(As + (wr + i * 16 + l16) * 32 + quad * 8);
#pragma unroll
    for (int j = 0; j < 4; ++j)
      bfr[j] = *(const bf16x8*)(Bs + (wc + j * 16 + l16) * 32 + quad * 8);
#pragma unroll
    for (int i = 0; i < 4; ++i)
#pragma unroll
      for (int j = 0; j < 4; ++j)
        acc[i][j] = __builtin_amdgcn_mfma_f32_16x16x32_bf16(af[i], bfr[j], acc[i][j], 0, 0, 0);
    __syncthreads();
  }

  // C/D layout: col = lane&15, row = (lane>>4)*4 + reg   [measured m89/m91]
#pragma unroll
  for (int j = 0; j < 4; ++j) {
    const size_t ng = n0 + wc + j * 16 + l16;
    const float bv = bias[ng];
#pragma unroll
    for (int i = 0; i < 4; ++i) {
      const size_t mg = m0 + wr + i * 16 + quad * 4;
#pragma unroll
      for (int r = 0; r < 4; ++r) {
        float v = acc[i][j][r] + bv;
        if (EPI == 1) v = 0.5f * v * (1.0f + erff(v * 0.70710678118654752f));
        if (EPI == 2) ((float*)outp)[(mg + r) * N + ng] = v;
        else          ((__bf16*)outp)[(mg + r) * N + ng] = (__bf16)v;
      }
    }
  }
}

// ---------------------------------------------------------------------------
// Per-token LayerNorm statistics (x in NCHW, coalesced over hw).
// ---------------------------------------------------------------------------
__global__ __launch_bounds__(256)
void ln_stats(const float* __restrict__ x, float* __restrict__ mean,
              float* __restrict__ rstd)
{
  const int b  = blockIdx.y;
  const int hw = blockIdx.x * 256 + threadIdx.x;
  if (hw >= HW_) return;
  const float* p = x + (size_t)b * (C_ * HW_) + hw;
  float s = 0.f, ss = 0.f;
  for (int c = 0; c < C_; ++c) {
    float v = p[(size_t)c * HW_];
    s += v; ss = fmaf(v, v, ss);
  }
  float mu  = s * (1.0f / C_);
  float var = ss * (1.0f / C_) - mu * mu;
  mean[b * HW_ + hw] = mu;
  rstd[b * HW_ + hw] = rsqrtf(var + EPS_);
}

// ---------------------------------------------------------------------------
// fp32 weight -> bf16 copies (qkv_w, proj_w, w1, w2), one launch.
// ---------------------------------------------------------------------------
__global__ __launch_bounds__(256)
void convert_weights(const float* __restrict__ a, const float* __restrict__ b,
                     const float* __restrict__ c, const float* __restrict__ d,
                     __bf16* __restrict__ oa, __bf16* __restrict__ ob,
                     __bf16* __restrict__ oc, __bf16* __restrict__ od)
{
  int i = blockIdx.x * 256 + threadIdx.x;
  if      (i < 442368)  oa[i] = (__bf16)a[i];
  else if (i < 589824)  ob[i - 442368]  = (__bf16)b[i - 442368];
  else if (i < 1179648) oc[i - 589824]  = (__bf16)c[i - 589824];
  else if (i < 1769472) od[i - 1179648] = (__bf16)d[i - 1179648];
}

// ---------------------------------------------------------------------------
// NCHW fp32 -> window-token-major bf16 (optionally with LayerNorm).
// ---------------------------------------------------------------------------
template <bool LN>
__global__ __launch_bounds__(256)
void win_gather(const float* __restrict__ src, const float* __restrict__ mean,
                const float* __restrict__ rstd, const float* __restrict__ gamma,
                const float* __restrict__ beta, __bf16* __restrict__ dst, int w0)
{
  const int win = w0 + blockIdx.x;
  const int b = win >> 6, wi = win & 63;
  const int hw0 = ((wi >> 3) * 56 + (wi & 7)) * 7;
  const float* xb = src + (size_t)b * (C_ * HW_) + hw0;
  const int tid = threadIdx.x;

  __shared__ float tile[64 * 49];
  __shared__ float mu_s[49], rs_s[49];
  if (LN && tid < 49) {
    int hw = hw0 + (tid / 7) * 56 + (tid % 7);
    mu_s[tid] = mean[b * HW_ + hw];
    rs_s[tid] = rstd[b * HW_ + hw];
  }
  for (int cb = 0; cb < C_; cb += 64) {
    for (int e = tid; e < 3136; e += 256) {      // e = cc*49 + n
      int cc = e / 49, n = e - cc * 49;
      tile[e] = xb[(size_t)(cb + cc) * HW_ + (n / 7) * 56 + (n % 7)];
    }
    __syncthreads();
    for (int e = tid; e < 3136; e += 256) {      // e = n*64 + cc
      int n = e >> 6, cc = e & 63;
      int ch = cb + cc;
      float v = tile[cc * 49 + n];
      if (LN) v = (v - mu_s[n]) * rs_s[n] * gamma[ch] + beta[ch];
      dst[((size_t)blockIdx.x * 49 + n) * C_ + ch] = (__bf16)v;
    }
    __syncthreads();
  }
}

// ---------------------------------------------------------------------------
// token-major fp32 [MC,384] -> NCHW.
// shortcut variant: outp_bf16 = xin + src   (seq, feeds dwconv only)
// accum variant:    outp_f32 += src          (MLP residual into d_out)
// ---------------------------------------------------------------------------
__global__ __launch_bounds__(256)
void win_scatter_shortcut(const float* __restrict__ src,
                          const float* __restrict__ xin,
                          __bf16* __restrict__ outp, int w0)
{
  const int win = w0 + blockIdx.x;
  const int b = win >> 6, wi = win & 63;
  const int hw0 = ((wi >> 3) * 56 + (wi & 7)) * 7;
  const size_t pbase = (size_t)b * (C_ * HW_) + hw0;
  const int tid = threadIdx.x;
  __shared__ float tile[64 * 49];

  for (int cb = 0; cb < C_; cb += 64) {
    for (int e = tid; e < 3136; e += 256) {      // e = n*64 + cc, coalesced read
      int n = e >> 6, cc = e & 63;
      tile[cc * 49 + n] = src[((size_t)blockIdx.x * 49 + n) * C_ + cb + cc];
    }
    __syncthreads();
    for (int e = tid; e < 3136; e += 256) {      // e = cc*49 + n
      int cc = e / 49, n = e - cc * 49;
      size_t idx = pbase + (size_t)(cb + cc) * HW_ + (n / 7) * 56 + (n % 7);
      outp[idx] = (__bf16)(xin[idx] + tile[e]);
    }
    __syncthreads();
  }
}

__global__ __launch_bounds__(256)
void win_scatter_accum(const float* __restrict__ src,
                       float* __restrict__ outp, int w0)
{
  const int win = w0 + blockIdx.x;
  const int b = win >> 6, wi = win & 63;
  const int hw0 = ((wi >> 3) * 56 + (wi & 7)) * 7;
  const size_t pbase = (size_t)b * (C_ * HW_) + hw0;
  const int tid = threadIdx.x;
  __shared__ float tile[64 * 49];

  for (int cb = 0; cb < C_; cb += 64) {
    for (int e = tid; e < 3136; e += 256) {
      int n = e >> 6, cc = e & 63;
      tile[cc * 49 + n] = src[((size_t)blockIdx.x * 49 + n) * C_ + cb + cc];
    }
    __syncthreads();
    for (int e = tid; e < 3136; e += 256) {
      int cc = e / 49, n = e - cc * 49;
      size_t idx = pbase + (size_t)(cb + cc) * HW_ + (n / 7) * 56 + (n % 7);
      outp[idx] += tile[e];
    }
    __syncthreads();
  }
}

// ---------------------------------------------------------------------------
// Window attention, one wave per (window, head). K,V staged fp32 in LDS;
// each of 49 lanes owns one query row fully in registers.
// ---------------------------------------------------------------------------
__global__ __launch_bounds__(64)
void attn_win(const __bf16* __restrict__ qkv, const float* __restrict__ btab,
              __bf16* __restrict__ attn_out)
{
  const int head = blockIdx.x;
  const int wl   = blockIdx.y;
  const int lane = threadIdx.x;

  __shared__ __align__(16) float ks[49 * 32];
  __shared__ __align__(16) float vs[49 * 32];
  __shared__ float bs[169];

  const __bf16* base = qkv + (size_t)wl * 49 * 1152 + head * 32;
  for (int e = lane; e < 1568; e += 64) {
    int n = e >> 5, d = e & 31;
    const __bf16* rowp = base + (size_t)n * 1152;
    ks[e] = (float)rowp[384 + d];
    vs[e] = (float)rowp[768 + d];
  }
  for (int e = lane; e < 169; e += 64) bs[e] = btab[e * 12 + head];
  __syncthreads();

  if (lane >= 49) return;
  const int ri = lane / 7, ci = lane % 7;
  float q[32];
  const __bf16* qp = base + (size_t)lane * 1152;
#pragma unroll
  for (int d = 0; d < 32; ++d) q[d] = (float)qp[d] * ASCAL;

  float p[49];
  float mx = -1e30f;
#pragma unroll
  for (int j = 0; j < 49; ++j) {
    float s = bs[(ri - j / 7 + 6) * 13 + (ci - j % 7 + 6)];
    const float* kj = ks + j * 32;
#pragma unroll
    for (int d = 0; d < 32; ++d) s = fmaf(q[d], kj[d], s);
    p[j] = s;
    mx = fmaxf(mx, s);
  }
  float sum = 0.f;
#pragma unroll
  for (int j = 0; j < 49; ++j) { float e = __expf(p[j] - mx); p[j] = e; sum += e; }
  const float inv = 1.0f / sum;

  float o[32];
#pragma unroll
  for (int d = 0; d < 32; ++d) o[d] = 0.f;
#pragma unroll
  for (int j = 0; j < 49; ++j) {
    const float pj = p[j];
    const float* vj = vs + j * 32;
#pragma unroll
    for (int d = 0; d < 32; ++d) o[d] = fmaf(pj, vj[d], o[d]);
  }
  __bf16* op = attn_out + ((size_t)wl * 49 + lane) * 384 + head * 32;
#pragma unroll
  for (int g = 0; g < 4; ++g) {
    bf16x8 t;
#pragma unroll
    for (int u = 0; u < 8; ++u) t[u] = (__bf16)(o[g * 8 + u] * inv);
    *(bf16x8*)(op + g * 8) = t;
  }
}

// ---------------------------------------------------------------------------
// Depthwise 3x3 conv (pad 1) + inference BN. One (b,c) plane per block;
// plane staged in LDS (bf16x8 coalesced loads), 9-tap from LDS, coalesced
// fp32 store into d_out (seq2). R2: was 9 scalar global loads/px @ 1TB/s.
// ---------------------------------------------------------------------------
__global__ __launch_bounds__(256)
void dwconv_bn(const __bf16* __restrict__ xc, const float* __restrict__ cw,
               const float* __restrict__ g, const float* __restrict__ bta,
               const float* __restrict__ mn, const float* __restrict__ vr,
               float* __restrict__ outp)
{
  const int bc = blockIdx.x;           // b*384 + c
  const int c  = bc % C_;
  const int tid = threadIdx.x;
  __shared__ float tile[HW_];

  const __bf16* pl = xc + (size_t)bc * HW_;
  for (int i = tid; i < 392; i += 256) {          // 392 * 8 = 3136
    bf16x8 v = ((const bf16x8*)pl)[i];
#pragma unroll
    for (int u = 0; u < 8; ++u) tile[i * 8 + u] = (float)v[u];
  }

  float wreg[9];
#pragma unroll
  for (int k = 0; k < 9; ++k) wreg[k] = cw[c * 9 + k];
  const float sc = g[c] * rsqrtf(vr[c] + EPS_);
  const float bb = bta[c] - mn[c] * sc;
  __syncthreads();

  for (int hw = tid; hw < HW_; hw += 256) {
    const int h = hw / 56, w = hw - h * 56;
    float a = 0.f;
#pragma unroll
    for (int kh = 0; kh < 3; ++kh) {
      const int hh = h + kh - 1;
      if ((unsigned)hh >= 56u) continue;
      const float* row = tile + hh * 56;
#pragma unroll
      for (int kw = 0; kw < 3; ++kw) {
        const int ww = w + kw - 1;
        if ((unsigned)ww >= 56u) continue;
        a = fmaf(wreg[kh * 3 + kw], row[ww], a);
      }
    }
    outp[(size_t)bc * HW_ + hw] = fmaf(a, sc, bb);
  }
}

// ---------------------------------------------------------------------------
extern "C" void kernel_launch(void* const* d_in, const int* in_sizes, int n_in,
                              void* d_out, int out_size, void* d_ws, size_t ws_size,
                              hipStream_t stream)
{
  const float* x      = (const float*)d_in[0];
  const float* ln_g   = (const float*)d_in[1];
  const float* ln_b   = (const float*)d_in[2];
  const float* qkv_w  = (const float*)d_in[3];
  const float* qkv_b  = (const float*)d_in[4];
  const float* proj_w = (const float*)d_in[5];
  const float* proj_b = (const float*)d_in[6];
  const float* btab   = (const float*)d_in[7];
  const float* conv_w = (const float*)d_in[8];
  const float* bn_g   = (const float*)d_in[9];
  const float* bn_b   = (const float*)d_in[10];
  const float* bn_m   = (const float*)d_in[11];
  const float* bn_v   = (const float*)d_in[12];
  const float* w1     = (const float*)d_in[13];
  const float* b1     = (const float*)d_in[14];
  const float* w2     = (const float*)d_in[15];
  const float* b2     = (const float*)d_in[16];
  float* out = (float*)d_out;

  size_t off = 0;
  auto alloc = [&](size_t bytes) -> void* {
    void* p = (char*)d_ws + off;
    off += (bytes + 255) & ~(size_t)255;
    return p;
  };
  float*  meanb = (float*)alloc((size_t)NTOK * 4);
  float*  rstdb = (float*)alloc((size_t)NTOK * 4);
  __bf16* wqb   = (__bf16*)alloc((size_t)1152 * 384 * 2);
  __bf16* wpb   = (__bf16*)alloc((size_t)384  * 384 * 2);
  __bf16* w1b   = (__bf16*)alloc((size_t)1536 * 384 * 2);
  __bf16* w2b   = (__bf16*)alloc((size_t)384  * 1536 * 2);
  __bf16* xconv = (__bf16*)alloc((size_t)NTOK * C_ * 2);   // seq, bf16 (R2)

  // Chunk size (tokens): 6144 B/token of chunk scratch.
  int MC = 6272;
  const int opts[5] = {100352, 50176, 25088, 12544, 6272};
  for (int i = 0; i < 5; ++i)
    if (off + (size_t)opts[i] * 6144 + 8192 <= ws_size) { MC = opts[i]; break; }

  __bf16* xn   = (__bf16*)alloc((size_t)MC * 384 * 2);   // ln(x) / seq2 tokens
  __bf16* qkvb = (__bf16*)alloc((size_t)MC * 1536 * 2);  // qkv, later MLP h
  __bf16* attb = (__bf16*)alloc((size_t)MC * 384 * 2);
  float*  ptmp = (float*)alloc((size_t)MC * 384 * 4);    // proj out / mlp2 out

  const int nchunks = NTOK / MC;
  const int wpc = MC / 49;   // windows per chunk

  convert_weights<<<6912, 256, 0, stream>>>(qkv_w, proj_w, w1, w2, wqb, wpb, w1b, w2b);
  ln_stats<<<dim3(13, NB_), 256, 0, stream>>>(x, meanb, rstdb);

  for (int ci = 0; ci < nchunks; ++ci) {
    const int w0 = ci * wpc;
    win_gather<true><<<wpc, 256, 0, stream>>>(x, meanb, rstdb, ln_g, ln_b, xn, w0);
    gemm_bt<0><<<dim3(9, MC / 128), 256, 0, stream>>>(xn, wqb, qkv_b, qkvb, MC, 1152, 384);
    attn_win<<<dim3(12, wpc), 64, 0, stream>>>(qkvb, btab, attb);
    gemm_bt<2><<<dim3(3, MC / 128), 256, 0, stream>>>(attb, wpb, proj_b, ptmp, MC, 384, 384);
    win_scatter_shortcut<<<wpc, 256, 0, stream>>>(ptmp, x, xconv, w0);
  }

  dwconv_bn<<<NB_ * C_, 256, 0, stream>>>(xconv, conv_w, bn_g, bn_b, bn_m, bn_v, out);

  for (int ci = 0; ci < nchunks; ++ci) {
    const int w0 = ci * wpc;
    win_gather<false><<<wpc, 256, 0, stream>>>(out, nullptr, nullptr, nullptr, nullptr, xn, w0);
    gemm_bt<1><<<dim3(12, MC / 128), 256, 0, stream>>>(xn, w1b, b1, qkvb, MC, 1536, 384);
    gemm_bt<2><<<dim3(3, MC / 128), 256, 0, stream>>>(qkvb, w2b, b2, ptmp, MC, 384, 1536);
    win_scatter_accum<<<wpc, 256, 0, stream>>>(ptmp, out, w0);
  }
}